// Round 4
// baseline (116.091 us; speedup 1.0000x reference)
//
#include <hip/hip_runtime.h>

#define NN 64
#define BB 8
#define HH 64
#define WW 64
#define EE 513
#define EQF -0.1f
#define IMG 4096
#define CHW 12288

typedef unsigned short u16;
typedef __attribute__((ext_vector_type(8))) short bf16x8;
typedef __attribute__((ext_vector_type(4))) float f32x4;

#define AI_NODE 131072      // u16 per node in actsI  [node][b][h][w][ci4]
#define WREG 6656           // bytes of LDS per wave (tiles 2x2560 union zbuf 6656)

__device__ __forceinline__ u16 f2bf(float f) {
  union { float f; unsigned u; } c; c.f = f;
  return (u16)((c.u + 0x7fffu + ((c.u >> 16) & 1u)) >> 16);
}

// ---------------- meta: CSR(+src resolve) + per-node bias sums + wfrag ----------------
__global__ __launch_bounds__(256) void meta_k(const float* __restrict__ conv_w,
                                              const float* __restrict__ conv_b,
                                              const int* __restrict__ src,
                                              const int* __restrict__ dst,
                                              u16* __restrict__ wfrag,
                                              int* __restrict__ csr_off,
                                              int2* __restrict__ csr2,
                                              float* __restrict__ nodeBias) {
  __shared__ int sdst[EE];
  __shared__ int ssrc[EE];
  __shared__ float sbias[EE * 3];
  __shared__ int scnt[NN];
  __shared__ int soff[NN + 1];
  int tid = threadIdx.x;
  if (blockIdx.x == 0) {
    for (int e = tid; e < EE; e += 256) { sdst[e] = dst[e]; ssrc[e] = src[e]; }
    for (int i = tid; i < EE * 3; i += 256) sbias[i] = conv_b[i];
    __syncthreads();
    if (tid < NN) {
      int c = 0;
      for (int e = 0; e < EE; ++e) c += (sdst[e] == tid) ? 1 : 0;
      scnt[tid] = c;
    }
    __syncthreads();
    if (tid == 0) {
      int s = 0;
      for (int n2 = 0; n2 < NN; ++n2) { soff[n2] = s; s += scnt[n2]; }
      soff[NN] = s;
    }
    __syncthreads();
    if (tid < NN) {
      int p = soff[tid];
      for (int e = 0; e < EE; ++e)
        if (sdst[e] == tid) { csr2[p] = make_int2(ssrc[e] * AI_NODE, e * 512); ++p; }
    } else if (tid < NN + 192 + 64) {
      int q = tid - NN - 64;           // tids 128..319 won't exist; use 64..255 below
      (void)q;
    }
    if (tid >= 64 && tid < 256) {
      int q = tid - 64;                // 0..191 = n*3+co
      int n = q / 3, co = q - n * 3;
      float s = 0.f;
      for (int e = 0; e < EE; ++e)
        if (sdst[e] == n) s += sbias[e * 3 + co];
      nodeBias[q] = s;
    }
    if (tid <= NN) csr_off[tid] = soff[tid];
  } else {
    int gid = (blockIdx.x - 1) * 256 + tid;
    if (gid < EE * 64) {
      int e = gid >> 6, l = gid & 63;
      int g = l >> 4, col = l & 15, co = col >> 2, kw = col & 3;
      u16 v[8];
      #pragma unroll
      for (int j = 0; j < 8; ++j) {
        float f = 0.0f;
        if (co < 3 && j < 3) f = conv_w[e * 144 + co * 48 + j * 16 + g * 4 + kw];
        v[j] = f2bf(f);
      }
      uint4 pk;
      pk.x = (unsigned)v[0] | ((unsigned)v[1] << 16);
      pk.y = (unsigned)v[2] | ((unsigned)v[3] << 16);
      pk.z = (unsigned)v[4] | ((unsigned)v[5] << 16);
      pk.w = (unsigned)v[6] | ((unsigned)v[7] << 16);
      *(uint4*)(wfrag + (size_t)gid * 8) = pk;
    }
  }
}

// ---------------- acts = sigmoid(states+noise) -> ci-interleaved bf16; node-N out copy ----------------
__global__ __launch_bounds__(256) void prep_k(const float* __restrict__ states,
                                              const float* __restrict__ noise,
                                              u16* __restrict__ actsI,
                                              float* __restrict__ out) {
  int idx = blockIdx.x * 256 + threadIdx.x;      // 65*8*64*16 = 532480 exact
  int w4 = idx & 15, h = (idx >> 4) & 63, b = (idx >> 10) & 7, n = idx >> 13;
  int pbase = (n * 8 + b) * CHW + h * 64 + w4 * 4;
  float4 s0 = *(const float4*)(states + pbase);
  float4 s1 = *(const float4*)(states + pbase + IMG);
  float4 s2 = *(const float4*)(states + pbase + 2 * IMG);
  float4 z0 = *(const float4*)(noise + pbase);
  float4 z1 = *(const float4*)(noise + pbase + IMG);
  float4 z2 = *(const float4*)(noise + pbase + 2 * IMG);
  float a0[4], a1[4], a2[4];
  #pragma unroll
  for (int p = 0; p < 4; ++p) {
    float v0 = ((const float*)&s0)[p] + ((const float*)&z0)[p];
    float v1 = ((const float*)&s1)[p] + ((const float*)&z1)[p];
    float v2 = ((const float*)&s2)[p] + ((const float*)&z2)[p];
    a0[p] = 1.0f / (1.0f + __expf(-v0));
    a1[p] = 1.0f / (1.0f + __expf(-v1));
    a2[p] = 1.0f / (1.0f + __expf(-v2));
  }
  uint4 q0, q1;
  q0.x = (unsigned)f2bf(a0[0]) | ((unsigned)f2bf(a1[0]) << 16);
  q0.y = (unsigned)f2bf(a2[0]);
  q0.z = (unsigned)f2bf(a0[1]) | ((unsigned)f2bf(a1[1]) << 16);
  q0.w = (unsigned)f2bf(a2[1]);
  q1.x = (unsigned)f2bf(a0[2]) | ((unsigned)f2bf(a1[2]) << 16);
  q1.y = (unsigned)f2bf(a2[2]);
  q1.z = (unsigned)f2bf(a0[3]) | ((unsigned)f2bf(a1[3]) << 16);
  q1.w = (unsigned)f2bf(a2[3]);
  u16* dp = actsI + ((size_t)(((n * 8 + b) * 64 + h) * 64) + w4 * 4) * 4;
  *(uint4*)dp = q0;
  *(uint4*)(dp + 8) = q1;
  if (n == NN) {
    *(float4*)(out + pbase) = s0;
    *(float4*)(out + pbase + IMG) = s1;
    *(float4*)(out + pbase + 2 * IMG) = s2;
  }
}

// ---------------- wave-autonomous MFMA conv + epilogue (no barriers) ----------------
__global__ __launch_bounds__(256, 4) void conv_k(const float* __restrict__ states,
                                                 const float* __restrict__ res,
                                                 const u16* __restrict__ actsI,
                                                 const u16* __restrict__ wfrag,
                                                 const int* __restrict__ csr_off,
                                                 const int2* __restrict__ csr2,
                                                 const float* __restrict__ nodeBias,
                                                 float* __restrict__ out) {
  __shared__ __align__(16) char smem[4 * WREG];   // 26624 B

  const int tid = threadIdx.x, lane = tid & 63, wid = tid >> 6;
  const int gw = blockIdx.x * 4 + wid;            // 16384 waves
  const int ht2 = gw & 31, b = (gw >> 5) & 7, n = gw >> 8;
  const int r0 = ht2 * 2;
  char* wbase = smem + wid * WREG;

  // staging piece params (5 rows x 8B per lane)
  int goff[5]; bool val[5];
  #pragma unroll
  for (int p = 0; p < 5; ++p) {
    int hin = r0 - 1 + p;
    val[p] = (hin >= 0) && (hin < HH);
    goff[p] = b * 16384 + hin * 256 + lane * 4;   // u16 units
  }
  // zero invalid rows once in both buffers
  {
    uint2 z2; z2.x = 0u; z2.y = 0u;
    #pragma unroll
    for (int p = 0; p < 5; ++p) if (!val[p]) {
      *(uint2*)(wbase + p * 512 + lane * 8) = z2;
      *(uint2*)(wbase + 2560 + p * 512 + lane * 8) = z2;
    }
  }
  const int abase = (lane >> 4) * 512 + (lane & 15) * 8;

  // epilogue global loads issued early (drained by loop vmcnts)
  float sreg[6], rreg[6]; int obase[6];
  #pragma unroll
  for (int h2 = 0; h2 < 2; ++h2)
    #pragma unroll
    for (int co = 0; co < 3; ++co) {
      int ix = h2 * 3 + co;
      obase[ix] = ((n * 8 + b) * 3 + co) * IMG + (r0 + h2) * 64 + lane;
      sreg[ix] = states[obase[ix]];
      rreg[ix] = res[obase[ix]];
    }

  f32x4 acc[2][4];
  #pragma unroll
  for (int h2 = 0; h2 < 2; ++h2)
    #pragma unroll
    for (int t = 0; t < 4; ++t) { acc[h2][t][0]=0.f; acc[h2][t][1]=0.f; acc[h2][t][2]=0.f; acc[h2][t][3]=0.f; }

  const int e0 = csr_off[n], e1 = csr_off[n + 1], cnt = e1 - e0;

  uint2 pA0, pA1, pA2, pA3, pA4; bf16x8 wfA;
  uint2 pB0, pB1, pB2, pB3, pB4; bf16x8 wfB;

#define LOADSET(P0,P1,P2,P3,P4,WF,IDX) do {                                   \
    int2 c_ = csr2[IDX];                                                      \
    int cx_ = __builtin_amdgcn_readfirstlane(c_.x);                           \
    int cy_ = __builtin_amdgcn_readfirstlane(c_.y);                           \
    const u16* ab_ = actsI + cx_;                                             \
    if (val[0]) P0 = *(const uint2*)(ab_ + goff[0]);                          \
    if (val[1]) P1 = *(const uint2*)(ab_ + goff[1]);                          \
    if (val[2]) P2 = *(const uint2*)(ab_ + goff[2]);                          \
    if (val[3]) P3 = *(const uint2*)(ab_ + goff[3]);                          \
    if (val[4]) P4 = *(const uint2*)(ab_ + goff[4]);                          \
    WF = *(const bf16x8*)(wfrag + cy_ + lane * 8);                            \
  } while (0)

#define STEP(P0,P1,P2,P3,P4,WF,BUFOFS,I) do {                                 \
    if (val[0]) *(uint2*)(wbase + (BUFOFS) + 0*512 + lane*8) = P0;            \
    if (val[1]) *(uint2*)(wbase + (BUFOFS) + 1*512 + lane*8) = P1;            \
    if (val[2]) *(uint2*)(wbase + (BUFOFS) + 2*512 + lane*8) = P2;            \
    if (val[3]) *(uint2*)(wbase + (BUFOFS) + 3*512 + lane*8) = P3;            \
    if (val[4]) *(uint2*)(wbase + (BUFOFS) + 4*512 + lane*8) = P4;            \
    bf16x8 cw_ = WF;                                                          \
    if ((I) + 2 < cnt) LOADSET(P0,P1,P2,P3,P4,WF, e0 + (I) + 2);              \
    _Pragma("unroll")                                                         \
    for (int h2 = 0; h2 < 2; ++h2) {                                          \
      _Pragma("unroll")                                                       \
      for (int t = 0; t < 4; ++t) {                                           \
        short4 d_ = *(const short4*)(wbase + (BUFOFS) + abase + h2*512 + t*128); \
        bf16x8 a_;                                                            \
        a_[0]=d_.x; a_[1]=d_.y; a_[2]=d_.z; a_[3]=d_.w;                       \
        a_[4]=0; a_[5]=0; a_[6]=0; a_[7]=0;                                   \
        acc[h2][t] = __builtin_amdgcn_mfma_f32_16x16x32_bf16(a_, cw_, acc[h2][t], 0, 0, 0); \
      }                                                                       \
    }                                                                         \
  } while (0)

  if (cnt > 0) LOADSET(pA0,pA1,pA2,pA3,pA4,wfA, e0);
  if (cnt > 1) LOADSET(pB0,pB1,pB2,pB3,pB4,wfB, e0 + 1);
  int i = 0;
  for (; i + 1 < cnt; i += 2) {
    STEP(pA0,pA1,pA2,pA3,pA4,wfA, 0,    i);
    STEP(pB0,pB1,pB2,pB3,pB4,wfB, 2560, i + 1);
  }
  if (i < cnt) STEP(pA0,pA1,pA2,pA3,pA4,wfA, 0, i);

  // ---- epilogue (wave-private zbuf overlaps dead tiles; same-wave ordering) ----
  float* zb = (float*)wbase;   // [2][64][13] f32
  const int col = lane & 15, g = lane >> 4;
  if (col < 12) {
    #pragma unroll
    for (int h2 = 0; h2 < 2; ++h2)
      #pragma unroll
      for (int t = 0; t < 4; ++t)
        #pragma unroll
        for (int r = 0; r < 4; ++r)
          zb[(h2 * 64 + t * 16 + g * 4 + r) * 13 + col] = acc[h2][t][r];
  }
  float bco0 = nodeBias[n * 3 + 0];
  float bco1 = nodeBias[n * 3 + 1];
  float bco2 = nodeBias[n * 3 + 2];
  #pragma unroll
  for (int h2 = 0; h2 < 2; ++h2) {
    #pragma unroll
    for (int co = 0; co < 3; ++co) {
      float y = (co == 0) ? bco0 : ((co == 1) ? bco1 : bco2);
      #pragma unroll
      for (int kw = 0; kw < 4; ++kw) {
        int wp = lane + kw - 1;
        if (wp >= 0 && wp < 64) y += zb[(h2 * 64 + wp) * 13 + co * 4 + kw];
      }
      int ix = h2 * 3 + co;
      float st = sreg[ix];
      out[obase[ix]] = st + fabsf(rreg[ix]) * (EQF - st) + y;
    }
  }
}

extern "C" void kernel_launch(void* const* d_in, const int* in_sizes, int n_in,
                              void* d_out, int out_size, void* d_ws, size_t ws_size,
                              hipStream_t stream) {
  const float* states = (const float*)d_in[0];
  const float* noise  = (const float*)d_in[1];
  const float* conv_w = (const float*)d_in[2];
  const float* conv_b = (const float*)d_in[3];
  const float* res    = (const float*)d_in[4];
  const int*   src    = (const int*)d_in[5];
  const int*   dst    = (const int*)d_in[6];
  float* out = (float*)d_out;

  u16* actsI = (u16*)d_ws;                                   // 17,039,360 B
  u16* wfrag = (u16*)((char*)d_ws + 17039360);               //    525,312 B -> ends 17,564,672
  int* csr_off = (int*)((char*)d_ws + 17564672);             // 80 ints -> ends 17,564,992
  int2* csr2 = (int2*)((char*)d_ws + 17564992);              // 513*8 B -> ends 17,569,096
  float* nodeBias = (float*)((char*)d_ws + 17569096);        // 192 floats

  meta_k<<<130, 256, 0, stream>>>(conv_w, conv_b, src, dst, wfrag, csr_off, csr2, nodeBias);
  prep_k<<<2080, 256, 0, stream>>>(states, noise, actsI, out);
  conv_k<<<4096, 256, 0, stream>>>(states, res, actsI, wfrag, csr_off, csr2, nodeBias, out);
}